// Round 21
// baseline (362.793 us; speedup 1.0000x reference)
//
#include <hip/hip_runtime.h>
#include <hip/hip_bf16.h>
#include <stdint.h>

typedef unsigned short u16;
typedef short short8 __attribute__((ext_vector_type(8)));
typedef short short4v __attribute__((ext_vector_type(4)));
typedef float f32x4 __attribute__((ext_vector_type(4)));

// scale folded into exp2: (1/sqrt(128)) * log2(e)
#define CSL (0.08838834764831845f * 1.4426950408889634f)
#define NEGR -1.0e13f   // raw-score mask value; *CSL -> -1.27e12 -> exp2 -> exactly 0

// B=2, S=2048, D=2048, H=16, DH=128.  M = B*S = 4096, N3 = 3*D = 6144, K = 2048.

__device__ __forceinline__ u16 f2b(float f) {
  union { float f; unsigned int u; } c; c.f = f;
  unsigned int u = c.u;
  u += 0x7fffu + ((u >> 16) & 1u);   // RNE; inputs are finite
  return (u16)(u >> 16);
}
__device__ __forceinline__ float b2f(u16 h) {
  union { float f; unsigned int u; } c; c.u = ((unsigned int)h) << 16;
  return c.f;
}

// ---------------- fused input casts: query f32->bf16 (blocks 0..4095) and
// W [2048][6144] f32 -> Wt [6144][2048] bf16 transpose-cast (blocks 4096..7167) ----------------
__global__ __launch_bounds__(256) void k_cast_fused(const float* __restrict__ q_in,
                                                    u16* __restrict__ qbf,
                                                    const float* __restrict__ W,
                                                    u16* __restrict__ Wt) {
  __shared__ u16 L[64 * 68];
  const int t = threadIdx.x;
  const int b = blockIdx.x;
  if (b < 4096) {
    size_t idx = ((size_t)b * 256 + t) * 8;
    float4 f0 = *(const float4*)(q_in + idx);
    float4 f1 = *(const float4*)(q_in + idx + 4);
    short8 o;
    o[0] = (short)f2b(f0.x); o[1] = (short)f2b(f0.y); o[2] = (short)f2b(f0.z); o[3] = (short)f2b(f0.w);
    o[4] = (short)f2b(f1.x); o[5] = (short)f2b(f1.y); o[6] = (short)f2b(f1.z); o[7] = (short)f2b(f1.w);
    *(short8*)(qbf + idx) = o;
    return;
  }
  const int wb = b - 4096;                 // 0..3071
  const int nb = (wb % 96) * 64;           // n base (0..6143)
  const int kb = (wb / 96) * 64;           // k base (0..2047)
#pragma unroll
  for (int it = 0; it < 4; ++it) {
    int idx = it * 1024 + t * 4;
    int r = idx >> 6, c = idx & 63;
    float4 f = *(const float4*)(W + (size_t)(kb + r) * 6144 + nb + c);
    L[r * 68 + c + 0] = f2b(f.x);
    L[r * 68 + c + 1] = f2b(f.y);
    L[r * 68 + c + 2] = f2b(f.z);
    L[r * 68 + c + 3] = f2b(f.w);
  }
  __syncthreads();
#pragma unroll
  for (int it = 0; it < 4; ++it) {
    int idx = it * 1024 + t * 4;
    int i = idx >> 6, j = idx & 63;
    short4v o;
#pragma unroll
    for (int e = 0; e < 4; ++e) o[e] = (short)L[(j + e) * 68 + i];
    *(short4v*)(Wt + (size_t)(nb + i) * 2048 + kb + j) = o;
  }
}

// ---------------- QKV GEMM, 128x192 tile, 2 BLOCKS/CU (R18 core) ----------------
// R21: V columns (ncol >= 4096) are written DIRECTLY into the head-transposed vt layout
// (vt[bh][d][s], s = (mrow&127)*16 + (nmod>>7), d = nmod&127) — eliminates the k_vtrans
// round-trip (16 MB read + 16 MB write + a launch).  Branch is wave-uniform (16-aligned
// lane groups never straddle the 2048/4096 boundaries).  Q/K epilogue unchanged.
__global__ __launch_bounds__(512, 4) void k_gemm128(const u16* __restrict__ A,
                                                    const u16* __restrict__ Bt,
                                                    const float* __restrict__ bias,
                                                    u16* __restrict__ qb,
                                                    u16* __restrict__ kbuf,
                                                    u16* __restrict__ vt) {
  __shared__ u16 As[2][8192];    // [dbuf][128 rows x 64 el], swizzled
  __shared__ u16 Bs[2][12288];   // [dbuf][192 rows x 64 el], swizzled
  const int t = threadIdx.x;
  const int ln = t & 63, w = t >> 6;
  const int lr = ln & 15, lg = ln >> 4;
  const int wm = w >> 2, wn = w & 3;           // 2 x 4 wave grid (wave tile 64x48)
  const int Lid = blockIdx.x;                  // 0..1023
  const int xcd = Lid & 7, l = Lid >> 3;       // 128 blocks per XCD
  const int mt = (xcd & 1) * 16 + (l & 15);    // supertile: 16m x 8n per XCD, m-fastest
  const int nt = (xcd >> 1) * 8 + (l >> 4);
  const int mb = mt * 128, nb = nt * 192;
  const int cswz = (lr & 7) * 8;               // read-side swizzle (elem)
  const int srow = w * 8 + (ln >> 3);          // staging row within 64-row part (0..63)
  const int scol = ((ln & 7) ^ (ln >> 3)) * 8; // pre-swizzled source col (elem)

  const u16* Abase = A + (size_t)mb * 2048;
  const u16* Bbase = Bt + (size_t)nb * 2048;

  f32x4 acc[4][3] = {};

  // full-tile stage: 2 A parts (128 rows) + 3 B parts (192 rows) = 5 wave-issues
#define STAGE_KT(kt_, buf_)                                                                        \
  do {                                                                                             \
    const u16* as_ = Abase + (size_t)srow * 2048 + (kt_) * 64 + scol;                              \
    const u16* bs_ = Bbase + (size_t)srow * 2048 + (kt_) * 64 + scol;                              \
    _Pragma("unroll")                                                                              \
    for (int p = 0; p < 2; ++p)                                                                    \
      __builtin_amdgcn_global_load_lds(                                                            \
          (const __attribute__((address_space(1))) void*)(as_ + (size_t)p * 64 * 2048),            \
          (__attribute__((address_space(3))) void*)(&As[buf_][p * 4096 + w * 512]), 16, 0, 0);     \
    _Pragma("unroll")                                                                              \
    for (int p = 0; p < 3; ++p)                                                                    \
      __builtin_amdgcn_global_load_lds(                                                            \
          (const __attribute__((address_space(1))) void*)(bs_ + (size_t)p * 64 * 2048),            \
          (__attribute__((address_space(3))) void*)(&Bs[buf_][p * 4096 + w * 512]), 16, 0, 0);     \
  } while (0)

  STAGE_KT(0, 0);
  asm volatile("s_waitcnt vmcnt(0)" ::: "memory");
  __builtin_amdgcn_s_barrier();

  for (int kt = 0; kt < 32; ++kt) {
    const int cur = kt & 1;
    const int ktn = (kt + 1) & 31;   // last iter: dummy re-stage of tile 0 (never read)
    const u16* At = &As[cur][0];
    const u16* Bl = &Bs[cur][0];

    STAGE_KT(ktn, cur ^ 1);                            // +5 in flight for kt+1
    asm volatile("s_waitcnt vmcnt(5)" ::: "memory");   // drain kt's 5; keep kt+1's flying
    __builtin_amdgcn_s_barrier();                      // kt's tile visible to all waves

    short8 af[4][2], bf[3][2];
#pragma unroll
    for (int mi = 0; mi < 4; ++mi)
#pragma unroll
      for (int ks = 0; ks < 2; ++ks)
        af[mi][ks] = *(const short8*)(At + (wm * 64 + mi * 16 + lr) * 64 + ((ks * 32 + lg * 8) ^ cswz));
#pragma unroll
    for (int ni = 0; ni < 3; ++ni)
#pragma unroll
      for (int ks = 0; ks < 2; ++ks)
        bf[ni][ks] = *(const short8*)(Bl + (wn * 48 + ni * 16 + lr) * 64 + ((ks * 32 + lg * 8) ^ cswz));

    __builtin_amdgcn_s_setprio(1);
#pragma unroll
    for (int ks = 0; ks < 2; ++ks)
#pragma unroll
      for (int mi = 0; mi < 4; ++mi)
#pragma unroll
        for (int ni = 0; ni < 3; ++ni)
          acc[mi][ni] = __builtin_amdgcn_mfma_f32_16x16x32_bf16(af[mi][ks], bf[ni][ks], acc[mi][ni], 0, 0, 0);
    __builtin_amdgcn_s_setprio(0);
    __builtin_amdgcn_s_barrier();                      // cur-buf reads done before next overwrite
  }
#undef STAGE_KT
  asm volatile("s_waitcnt vmcnt(0)" ::: "memory");  // drain dummy stage before epilogue

  // epilogue: bias + routing.  Q/K: row-major write.  V: direct head-transposed vt write.
#pragma unroll
  for (int ni = 0; ni < 3; ++ni) {
    int ncol = nb + wn * 48 + ni * 16 + lr;
    float bv = bias[ncol];
    if (ncol < 4096) {
      u16* dst = (ncol < 2048) ? qb : kbuf;
      int nmod = ncol & 2047;
#pragma unroll
      for (int mi = 0; mi < 4; ++mi) {
#pragma unroll
        for (int r = 0; r < 4; ++r) {
          int mrow = mb + wm * 64 + mi * 16 + lg * 4 + r;
          dst[(size_t)mrow * 2048 + nmod] = f2b(acc[mi][ni][r] + bv);
        }
      }
    } else {
      int nmod = ncol - 4096;
      int d = nmod & 127, shi = nmod >> 7;   // head-local s = (mrow&127)*16 + shi
#pragma unroll
      for (int mi = 0; mi < 4; ++mi) {
#pragma unroll
        for (int r = 0; r < 4; ++r) {
          int mrow = mb + wm * 64 + mi * 16 + lg * 4 + r;
          int bh = mrow >> 7;                // b*16 + h  (since mrow = b*2048 + h*128 + rl)
          int rl = mrow & 127;
          vt[((size_t)bh << 18) + (size_t)d * 2048 + rl * 16 + shi] = f2b(acc[mi][ni][r] + bv);
        }
      }
    }
  }
}

// ---------------- V column partial sums from vt: part[bh][sc][d] = sum_{s in chunk} V[s][d] ----------------
__global__ __launch_bounds__(256) void k_vpart(const u16* __restrict__ vt, float* __restrict__ part) {
  __shared__ float L[256];
  const int t = threadIdx.x;
  const int sc = blockIdx.x, bh = blockIdx.y;   // 16 x 32
  const int d = t >> 1, half = t & 1;
  const u16* p = vt + ((size_t)bh << 18) + (size_t)d * 2048 + sc * 128 + half * 64;
  float s = 0.f;
#pragma unroll
  for (int i = 0; i < 8; ++i) {
    short8 v = *(const short8*)(p + i * 8);
#pragma unroll
    for (int e = 0; e < 8; ++e) s += b2f((u16)v[e]);
  }
  L[t] = s;
  __syncthreads();
  if (half == 0) part[((size_t)bh * 16 + sc) * 128 + d] = L[t] + L[t + 1];
}

// ---------------- flash attention: async global_load_lds staging + T2-swizzled unpadded LDS ----------------
// (exact R17/R20 version, __launch_bounds__(256,3) — measured ~67 us)
__global__ __launch_bounds__(256, 3) void k_attn(const u16* __restrict__ qb,
                                                 const u16* __restrict__ kb,
                                                 const u16* __restrict__ vt,
                                                 const float* __restrict__ part,
                                                 float* __restrict__ out) {
  __shared__ u16 Ks[64 * 128];   // [sk][d], swizzled, no pad
  __shared__ u16 Vs[128 * 64];   // V^T [dh][sk], swizzled, no pad
  __shared__ u16 Ps[4][16 * 64]; // per-wave P [qrow][sk], swizzled, no pad
  const int t = threadIdx.x;
  const int ln = t & 63, wv = t >> 6;
  const int lr = ln & 15, lg = ln >> 4;
  const int lr7 = lr & 7;
  const int L = blockIdx.y * 32 + blockIdx.x;      // launched linear id (x fastest), 0..1023
  const int wl = (L & 7) * 128 + (L >> 3);         // bijective XCD-aware remap (1024 blocks)
  const int bh = wl >> 5;                          // 4 heads per XCD chunk of 128 blocks
  const int qt = 31 - (wl & 31);                   // long strips first in dispatch order
  const size_t base = (size_t)bh * 262144;  // contiguous [2048][128] per head
  const u16* Qh = qb + base;
  const u16* Kh = kb + base;
  const u16* Vth = vt + base;
  float* Oh = out + base;
  const int qs = qt * 64;

  short8 qf[4];
  {
    int qr = qs + wv * 16 + lr;
#pragma unroll
    for (int ks = 0; ks < 4; ++ks)
      qf[ks] = *(const short8*)(Qh + (size_t)qr * 128 + ks * 32 + lg * 8);
  }
  float lsum[4] = {0.f, 0.f, 0.f, 0.f};  // lane-local partial row-sums
  f32x4 acc[8];
  const f32x4 fz = {0.f, 0.f, 0.f, 0.f};
#pragma unroll
  for (int oj = 0; oj < 8; ++oj) acc[oj] = fz;

  u16* Pw = &Ps[wv][0];
  const int nkt = qt + 1;
  for (int kt = 0; kt < nkt; ++kt) {
    // stage K [64][128]: dest chunk l=(sk,c8) <- source col-chunk c8^(sk&7)  (async, issue-only)
#pragma unroll
    for (int it = 0; it < 4; ++it) {
      int chunk = it * 256 + wv * 64 + ln;
      int sk = chunk >> 4, c8 = (chunk & 15) ^ (sk & 7);
      __builtin_amdgcn_global_load_lds(
          (const __attribute__((address_space(1))) void*)(Kh + (size_t)(kt * 64 + sk) * 128 + c8 * 8),
          (__attribute__((address_space(3))) void*)(Ks + (size_t)(it * 256 + wv * 64) * 8),
          16, 0, 0);
    }
    // stage V^T [128][64]: dest chunk l=(dh,c8) <- source col-chunk c8^(dh&7)
#pragma unroll
    for (int it = 0; it < 4; ++it) {
      int chunk = it * 256 + wv * 64 + ln;
      int dh = chunk >> 3, c8 = (chunk & 7) ^ (dh & 7);
      __builtin_amdgcn_global_load_lds(
          (const __attribute__((address_space(1))) void*)(Vth + (size_t)dh * 2048 + kt * 64 + c8 * 8),
          (__attribute__((address_space(3))) void*)(Vs + (size_t)(it * 256 + wv * 64) * 8),
          16, 0, 0);
    }
    __syncthreads();  // drains vmcnt -> staged tile visible

    f32x4 s[4];
#pragma unroll
    for (int ni = 0; ni < 4; ++ni) s[ni] = fz;
#pragma unroll
    for (int ks = 0; ks < 4; ++ks) {
#pragma unroll
      for (int ni = 0; ni < 4; ++ni) {
        short8 kf = *(const short8*)(Ks + (ni * 16 + lr) * 128 + ((ks * 4 + lg) ^ lr7) * 8);
        s[ni] = __builtin_amdgcn_mfma_f32_16x16x32_bf16(qf[ks], kf, s[ni], 0, 0, 0);
      }
    }
    if (kt == qt) {  // diagonal tile: mask col >= row (diagonal included)
#pragma unroll
      for (int ni = 0; ni < 4; ++ni) {
        int col = kt * 64 + ni * 16 + lr;
#pragma unroll
        for (int r = 0; r < 4; ++r) {
          int row = qs + wv * 16 + lg * 4 + r;
          if (col >= row) s[ni][r] = NEGR;
        }
      }
    }
#pragma unroll
    for (int ni = 0; ni < 4; ++ni)
#pragma unroll
      for (int r = 0; r < 4; ++r) {
        u16 h = f2b(exp2f(s[ni][r] * CSL));
        int pr = lg * 4 + r, pc = ni * 16 + lr;
        Pw[pr * 64 + ((pc >> 3) ^ (pr & 7)) * 8 + (pc & 7)] = h;
        lsum[r] += b2f(h);   // denominator from the same rounded weights PV uses
      }
#pragma unroll
    for (int ks2 = 0; ks2 < 2; ++ks2) {
      short8 pa = *(const short8*)(Pw + lr * 64 + ((ks2 * 4 + lg) ^ lr7) * 8);
#pragma unroll
      for (int oj = 0; oj < 8; ++oj) {
        short8 vf = *(const short8*)(Vs + (oj * 16 + lr) * 64 + ((ks2 * 4 + lg) ^ lr7) * 8);
        acc[oj] = __builtin_amdgcn_mfma_f32_16x16x32_bf16(pa, vf, acc[oj], 0, 0, 0);
      }
    }
    __syncthreads();  // all waves done reading before next tile's staging overwrites
  }

  // epilogue: single cross-lane reduction of the row-sums, then divide.
  float rl[4];
#pragma unroll
  for (int r = 0; r < 4; ++r) {
    float sa = lsum[r];
#pragma unroll
    for (int d = 1; d < 16; d <<= 1) sa += __shfl_xor(sa, d, 64);
    rl[r] = 1.0f / sa;  // row 0 gives inf; overwritten analytically below
  }
#pragma unroll
  for (int oj = 0; oj < 8; ++oj)
#pragma unroll
    for (int r = 0; r < 4; ++r) {
      int row = qs + wv * 16 + lg * 4 + r;
      float val = acc[oj][r] * rl[r];
      if (qt == 0 && wv == 0 && lg == 0 && r == 0) {
        float vs = 0.f;
#pragma unroll
        for (int sc = 0; sc < 16; ++sc) vs += part[(size_t)bh * 2048 + sc * 128 + oj * 16 + lr];
        val = vs * (1.0f / 2048.0f);
      }
      Oh[(size_t)row * 128 + oj * 16 + lr] = val;
    }
}

extern "C" void kernel_launch(void* const* d_in, const int* in_sizes, int n_in,
                              void* d_out, int out_size, void* d_ws, size_t ws_size,
                              hipStream_t stream) {
  (void)in_sizes; (void)n_in; (void)out_size; (void)ws_size;
  const float* q_in = (const float*)d_in[0];
  const float* W = (const float*)d_in[3];
  const float* bias = (const float*)d_in[4];
  float* out = (float*)d_out;

  // workspace layout (bf16 elements unless noted)
  u16* qbf = (u16*)d_ws;                      // 4096*2048
  u16* wtb = qbf + (size_t)4096 * 2048;       // 6144*2048
  u16* qb  = wtb + (size_t)6144 * 2048;       // 4096*2048
  u16* kbf = qb  + (size_t)4096 * 2048;       // 4096*2048
  u16* vt  = kbf + (size_t)4096 * 2048;       // 4096*2048  V^T per head [bh][128][2048]
  float* part = (float*)(vt + (size_t)4096 * 2048);  // [32][16][128] f32 col-chunk sums

  k_cast_fused<<<7168, 256, 0, stream>>>(q_in, qbf, W, wtb);
  k_gemm128<<<1024, 512, 0, stream>>>(qbf, wtb, bias, qb, kbf, vt);
  k_vpart<<<dim3(16, 32), 256, 0, stream>>>(vt, part);
  k_attn<<<dim3(32, 32), 256, 0, stream>>>(qb, kbf, vt, part, out);
}

// Round 22
// 218.593 us; speedup vs baseline: 1.6597x; 1.6597x over previous
//
#include <hip/hip_runtime.h>
#include <hip/hip_bf16.h>
#include <stdint.h>

typedef unsigned short u16;
typedef short short8 __attribute__((ext_vector_type(8)));
typedef short short4v __attribute__((ext_vector_type(4)));
typedef float f32x4 __attribute__((ext_vector_type(4)));

// scale folded into exp2: (1/sqrt(128)) * log2(e)
#define CSL (0.08838834764831845f * 1.4426950408889634f)
#define NEGR -1.0e13f   // raw-score mask value; *CSL -> -1.27e12 -> exp2 -> exactly 0

// B=2, S=2048, D=2048, H=16, DH=128.  M = B*S = 4096, N3 = 3*D = 6144, K = 2048.

__device__ __forceinline__ u16 f2b(float f) {
  union { float f; unsigned int u; } c; c.f = f;
  unsigned int u = c.u;
  u += 0x7fffu + ((u >> 16) & 1u);   // RNE; inputs are finite
  return (u16)(u >> 16);
}
__device__ __forceinline__ float b2f(u16 h) {
  union { float f; unsigned int u; } c; c.u = ((unsigned int)h) << 16;
  return c.f;
}

// ---------------- fused input casts: query f32->bf16 (blocks 0..4095) and
// W [2048][6144] f32 -> Wt [6144][2048] bf16 transpose-cast (blocks 4096..7167) ----------------
__global__ __launch_bounds__(256) void k_cast_fused(const float* __restrict__ q_in,
                                                    u16* __restrict__ qbf,
                                                    const float* __restrict__ W,
                                                    u16* __restrict__ Wt) {
  __shared__ u16 L[64 * 68];
  const int t = threadIdx.x;
  const int b = blockIdx.x;
  if (b < 4096) {
    size_t idx = ((size_t)b * 256 + t) * 8;
    float4 f0 = *(const float4*)(q_in + idx);
    float4 f1 = *(const float4*)(q_in + idx + 4);
    short8 o;
    o[0] = (short)f2b(f0.x); o[1] = (short)f2b(f0.y); o[2] = (short)f2b(f0.z); o[3] = (short)f2b(f0.w);
    o[4] = (short)f2b(f1.x); o[5] = (short)f2b(f1.y); o[6] = (short)f2b(f1.z); o[7] = (short)f2b(f1.w);
    *(short8*)(qbf + idx) = o;
    return;
  }
  const int wb = b - 4096;                 // 0..3071
  const int nb = (wb % 96) * 64;           // n base (0..6143)
  const int kb = (wb / 96) * 64;           // k base (0..2047)
#pragma unroll
  for (int it = 0; it < 4; ++it) {
    int idx = it * 1024 + t * 4;
    int r = idx >> 6, c = idx & 63;
    float4 f = *(const float4*)(W + (size_t)(kb + r) * 6144 + nb + c);
    L[r * 68 + c + 0] = f2b(f.x);
    L[r * 68 + c + 1] = f2b(f.y);
    L[r * 68 + c + 2] = f2b(f.z);
    L[r * 68 + c + 3] = f2b(f.w);
  }
  __syncthreads();
#pragma unroll
  for (int it = 0; it < 4; ++it) {
    int idx = it * 1024 + t * 4;
    int i = idx >> 6, j = idx & 63;
    short4v o;
#pragma unroll
    for (int e = 0; e < 4; ++e) o[e] = (short)L[(j + e) * 68 + i];
    *(short4v*)(Wt + (size_t)(nb + i) * 2048 + kb + j) = o;
  }
}

// ---------------- QKV GEMM, 128x192 tile, 2 BLOCKS/CU (exact R18/R20 version, ~125 us) ----------------
__global__ __launch_bounds__(512, 4) void k_gemm128(const u16* __restrict__ A,
                                                    const u16* __restrict__ Bt,
                                                    const float* __restrict__ bias,
                                                    u16* __restrict__ qb,
                                                    u16* __restrict__ kbuf,
                                                    u16* __restrict__ vbuf) {
  __shared__ u16 As[2][8192];    // [dbuf][128 rows x 64 el], swizzled
  __shared__ u16 Bs[2][12288];   // [dbuf][192 rows x 64 el], swizzled
  const int t = threadIdx.x;
  const int ln = t & 63, w = t >> 6;
  const int lr = ln & 15, lg = ln >> 4;
  const int wm = w >> 2, wn = w & 3;           // 2 x 4 wave grid (wave tile 64x48)
  const int Lid = blockIdx.x;                  // 0..1023
  const int xcd = Lid & 7, l = Lid >> 3;       // 128 blocks per XCD
  const int mt = (xcd & 1) * 16 + (l & 15);    // supertile: 16m x 8n per XCD, m-fastest
  const int nt = (xcd >> 1) * 8 + (l >> 4);
  const int mb = mt * 128, nb = nt * 192;
  const int cswz = (lr & 7) * 8;               // read-side swizzle (elem)
  const int srow = w * 8 + (ln >> 3);          // staging row within 64-row part (0..63)
  const int scol = ((ln & 7) ^ (ln >> 3)) * 8; // pre-swizzled source col (elem)

  const u16* Abase = A + (size_t)mb * 2048;
  const u16* Bbase = Bt + (size_t)nb * 2048;

  f32x4 acc[4][3] = {};

  // full-tile stage: 2 A parts (128 rows) + 3 B parts (192 rows) = 5 wave-issues
#define STAGE_KT(kt_, buf_)                                                                        \
  do {                                                                                             \
    const u16* as_ = Abase + (size_t)srow * 2048 + (kt_) * 64 + scol;                              \
    const u16* bs_ = Bbase + (size_t)srow * 2048 + (kt_) * 64 + scol;                              \
    _Pragma("unroll")                                                                              \
    for (int p = 0; p < 2; ++p)                                                                    \
      __builtin_amdgcn_global_load_lds(                                                            \
          (const __attribute__((address_space(1))) void*)(as_ + (size_t)p * 64 * 2048),            \
          (__attribute__((address_space(3))) void*)(&As[buf_][p * 4096 + w * 512]), 16, 0, 0);     \
    _Pragma("unroll")                                                                              \
    for (int p = 0; p < 3; ++p)                                                                    \
      __builtin_amdgcn_global_load_lds(                                                            \
          (const __attribute__((address_space(1))) void*)(bs_ + (size_t)p * 64 * 2048),            \
          (__attribute__((address_space(3))) void*)(&Bs[buf_][p * 4096 + w * 512]), 16, 0, 0);     \
  } while (0)

  STAGE_KT(0, 0);
  asm volatile("s_waitcnt vmcnt(0)" ::: "memory");
  __builtin_amdgcn_s_barrier();

  for (int kt = 0; kt < 32; ++kt) {
    const int cur = kt & 1;
    const int ktn = (kt + 1) & 31;   // last iter: dummy re-stage of tile 0 (never read)
    const u16* At = &As[cur][0];
    const u16* Bl = &Bs[cur][0];

    STAGE_KT(ktn, cur ^ 1);                            // +5 in flight for kt+1
    asm volatile("s_waitcnt vmcnt(5)" ::: "memory");   // drain kt's 5; keep kt+1's flying
    __builtin_amdgcn_s_barrier();                      // kt's tile visible to all waves

    short8 af[4][2], bf[3][2];
#pragma unroll
    for (int mi = 0; mi < 4; ++mi)
#pragma unroll
      for (int ks = 0; ks < 2; ++ks)
        af[mi][ks] = *(const short8*)(At + (wm * 64 + mi * 16 + lr) * 64 + ((ks * 32 + lg * 8) ^ cswz));
#pragma unroll
    for (int ni = 0; ni < 3; ++ni)
#pragma unroll
      for (int ks = 0; ks < 2; ++ks)
        bf[ni][ks] = *(const short8*)(Bl + (wn * 48 + ni * 16 + lr) * 64 + ((ks * 32 + lg * 8) ^ cswz));

    __builtin_amdgcn_s_setprio(1);
#pragma unroll
    for (int ks = 0; ks < 2; ++ks)
#pragma unroll
      for (int mi = 0; mi < 4; ++mi)
#pragma unroll
        for (int ni = 0; ni < 3; ++ni)
          acc[mi][ni] = __builtin_amdgcn_mfma_f32_16x16x32_bf16(af[mi][ks], bf[ni][ks], acc[mi][ni], 0, 0, 0);
    __builtin_amdgcn_s_setprio(0);
    __builtin_amdgcn_s_barrier();                      // cur-buf reads done before next overwrite
  }
#undef STAGE_KT
  asm volatile("s_waitcnt vmcnt(0)" ::: "memory");  // drain dummy stage before epilogue

  // epilogue: bias + per-(wn,ni) q/k/v routing (16-col lane groups are 16-aligned; 2048 % 16 == 0
  // so a group never straddles the q/k/v boundary -> dst uniform per group)
#pragma unroll
  for (int ni = 0; ni < 3; ++ni) {
    int ncol = nb + wn * 48 + ni * 16 + lr;
    u16* dst = (ncol < 2048) ? qb : (ncol < 4096 ? kbuf : vbuf);
    int nmod = ncol & 2047;
    float bv = bias[ncol];
#pragma unroll
    for (int mi = 0; mi < 4; ++mi) {
#pragma unroll
      for (int r = 0; r < 4; ++r) {
        int mrow = mb + wm * 64 + mi * 16 + lg * 4 + r;
        dst[(size_t)mrow * 2048 + nmod] = f2b(acc[mi][ni][r] + bv);
      }
    }
  }
}

// ---------------- V transpose + column partial sums ----------------
__global__ __launch_bounds__(256) void k_vtrans(const u16* __restrict__ v, u16* __restrict__ vt,
                                                float* __restrict__ part) {
  __shared__ u16 L[128 * 136];
  __shared__ float Ls2[256];
  const int t = threadIdx.x;
  const int bh = blockIdx.y, sc = blockIdx.x;  // sc: 128-row s-chunk, 0..15
  const size_t base = (size_t)bh * 262144;
#pragma unroll
  for (int it = 0; it < 8; ++it) {
    int chunk = it * 256 + t;
    int s = chunk >> 4, d8 = (chunk & 15) * 8;
    *(short8*)(L + s * 136 + d8) = *(const short8*)(v + base + (size_t)(sc * 128 + s) * 128 + d8);
  }
  __syncthreads();
#pragma unroll
  for (int it = 0; it < 8; ++it) {
    int chunk = it * 256 + t;
    int dh = chunk >> 4, s8 = (chunk & 15) * 8;
    short8 o;
#pragma unroll
    for (int e = 0; e < 8; ++e) o[e] = (short)L[(s8 + e) * 136 + dh];
    *(short8*)(vt + base + (size_t)dh * 2048 + sc * 128 + s8) = o;
  }
  {
    const int dh = t & 127, seg = t >> 7;
    float ps = 0.f;
#pragma unroll 8
    for (int i = 0; i < 64; ++i) ps += b2f(L[(seg * 64 + i) * 136 + dh]);
    Ls2[t] = ps;
    __syncthreads();
    if (t < 128) part[((size_t)bh * 16 + sc) * 128 + t] = Ls2[t] + Ls2[t + 128];
  }
}

// ---------------- flash attention: async global_load_lds staging + T2-swizzled unpadded LDS ----------------
// (exact R17/R20 version, __launch_bounds__(256,3) — measured ~67 us)
__global__ __launch_bounds__(256, 3) void k_attn(const u16* __restrict__ qb,
                                                 const u16* __restrict__ kb,
                                                 const u16* __restrict__ vt,
                                                 const float* __restrict__ part,
                                                 float* __restrict__ out) {
  __shared__ u16 Ks[64 * 128];   // [sk][d], swizzled, no pad
  __shared__ u16 Vs[128 * 64];   // V^T [dh][sk], swizzled, no pad
  __shared__ u16 Ps[4][16 * 64]; // per-wave P [qrow][sk], swizzled, no pad
  const int t = threadIdx.x;
  const int ln = t & 63, wv = t >> 6;
  const int lr = ln & 15, lg = ln >> 4;
  const int lr7 = lr & 7;
  const int L = blockIdx.y * 32 + blockIdx.x;      // launched linear id (x fastest), 0..1023
  const int wl = (L & 7) * 128 + (L >> 3);         // bijective XCD-aware remap (1024 blocks)
  const int bh = wl >> 5;                          // 4 heads per XCD chunk of 128 blocks
  const int qt = 31 - (wl & 31);                   // long strips first in dispatch order
  const size_t base = (size_t)bh * 262144;  // contiguous [2048][128] per head
  const u16* Qh = qb + base;
  const u16* Kh = kb + base;
  const u16* Vth = vt + base;
  float* Oh = out + base;
  const int qs = qt * 64;

  short8 qf[4];
  {
    int qr = qs + wv * 16 + lr;
#pragma unroll
    for (int ks = 0; ks < 4; ++ks)
      qf[ks] = *(const short8*)(Qh + (size_t)qr * 128 + ks * 32 + lg * 8);
  }
  float lsum[4] = {0.f, 0.f, 0.f, 0.f};  // lane-local partial row-sums
  f32x4 acc[8];
  const f32x4 fz = {0.f, 0.f, 0.f, 0.f};
#pragma unroll
  for (int oj = 0; oj < 8; ++oj) acc[oj] = fz;

  u16* Pw = &Ps[wv][0];
  const int nkt = qt + 1;
  for (int kt = 0; kt < nkt; ++kt) {
    // stage K [64][128]: dest chunk l=(sk,c8) <- source col-chunk c8^(sk&7)  (async, issue-only)
#pragma unroll
    for (int it = 0; it < 4; ++it) {
      int chunk = it * 256 + wv * 64 + ln;
      int sk = chunk >> 4, c8 = (chunk & 15) ^ (sk & 7);
      __builtin_amdgcn_global_load_lds(
          (const __attribute__((address_space(1))) void*)(Kh + (size_t)(kt * 64 + sk) * 128 + c8 * 8),
          (__attribute__((address_space(3))) void*)(Ks + (size_t)(it * 256 + wv * 64) * 8),
          16, 0, 0);
    }
    // stage V^T [128][64]: dest chunk l=(dh,c8) <- source col-chunk c8^(dh&7)
#pragma unroll
    for (int it = 0; it < 4; ++it) {
      int chunk = it * 256 + wv * 64 + ln;
      int dh = chunk >> 3, c8 = (chunk & 7) ^ (dh & 7);
      __builtin_amdgcn_global_load_lds(
          (const __attribute__((address_space(1))) void*)(Vth + (size_t)dh * 2048 + kt * 64 + c8 * 8),
          (__attribute__((address_space(3))) void*)(Vs + (size_t)(it * 256 + wv * 64) * 8),
          16, 0, 0);
    }
    __syncthreads();  // drains vmcnt -> staged tile visible

    f32x4 s[4];
#pragma unroll
    for (int ni = 0; ni < 4; ++ni) s[ni] = fz;
#pragma unroll
    for (int ks = 0; ks < 4; ++ks) {
#pragma unroll
      for (int ni = 0; ni < 4; ++ni) {
        short8 kf = *(const short8*)(Ks + (ni * 16 + lr) * 128 + ((ks * 4 + lg) ^ lr7) * 8);
        s[ni] = __builtin_amdgcn_mfma_f32_16x16x32_bf16(qf[ks], kf, s[ni], 0, 0, 0);
      }
    }
    if (kt == qt) {  // diagonal tile: mask col >= row (diagonal included)
#pragma unroll
      for (int ni = 0; ni < 4; ++ni) {
        int col = kt * 64 + ni * 16 + lr;
#pragma unroll
        for (int r = 0; r < 4; ++r) {
          int row = qs + wv * 16 + lg * 4 + r;
          if (col >= row) s[ni][r] = NEGR;
        }
      }
    }
#pragma unroll
    for (int ni = 0; ni < 4; ++ni)
#pragma unroll
      for (int r = 0; r < 4; ++r) {
        u16 h = f2b(exp2f(s[ni][r] * CSL));
        int pr = lg * 4 + r, pc = ni * 16 + lr;
        Pw[pr * 64 + ((pc >> 3) ^ (pr & 7)) * 8 + (pc & 7)] = h;
        lsum[r] += b2f(h);   // denominator from the same rounded weights PV uses
      }
#pragma unroll
    for (int ks2 = 0; ks2 < 2; ++ks2) {
      short8 pa = *(const short8*)(Pw + lr * 64 + ((ks2 * 4 + lg) ^ lr7) * 8);
#pragma unroll
      for (int oj = 0; oj < 8; ++oj) {
        short8 vf = *(const short8*)(Vs + (oj * 16 + lr) * 64 + ((ks2 * 4 + lg) ^ lr7) * 8);
        acc[oj] = __builtin_amdgcn_mfma_f32_16x16x32_bf16(pa, vf, acc[oj], 0, 0, 0);
      }
    }
    __syncthreads();  // all waves done reading before next tile's staging overwrites
  }

  // epilogue: single cross-lane reduction of the row-sums, then divide.
  float rl[4];
#pragma unroll
  for (int r = 0; r < 4; ++r) {
    float sa = lsum[r];
#pragma unroll
    for (int d = 1; d < 16; d <<= 1) sa += __shfl_xor(sa, d, 64);
    rl[r] = 1.0f / sa;  // row 0 gives inf; overwritten analytically below
  }
#pragma unroll
  for (int oj = 0; oj < 8; ++oj)
#pragma unroll
    for (int r = 0; r < 4; ++r) {
      int row = qs + wv * 16 + lg * 4 + r;
      float val = acc[oj][r] * rl[r];
      if (qt == 0 && wv == 0 && lg == 0 && r == 0) {
        float vs = 0.f;
#pragma unroll
        for (int sc = 0; sc < 16; ++sc) vs += part[(size_t)bh * 2048 + sc * 128 + oj * 16 + lr];
        val = vs * (1.0f / 2048.0f);
      }
      Oh[(size_t)row * 128 + oj * 16 + lr] = val;
    }
}

extern "C" void kernel_launch(void* const* d_in, const int* in_sizes, int n_in,
                              void* d_out, int out_size, void* d_ws, size_t ws_size,
                              hipStream_t stream) {
  (void)in_sizes; (void)n_in; (void)out_size; (void)ws_size;
  const float* q_in = (const float*)d_in[0];
  const float* W = (const float*)d_in[3];
  const float* bias = (const float*)d_in[4];
  float* out = (float*)d_out;

  // workspace layout (bf16 elements unless noted); total ~109.3 MB
  u16* qbf = (u16*)d_ws;                      // 4096*2048
  u16* wtb = qbf + (size_t)4096 * 2048;       // 6144*2048
  u16* qb  = wtb + (size_t)6144 * 2048;       // 4096*2048
  u16* kbf = qb  + (size_t)4096 * 2048;       // 4096*2048
  u16* vbf = kbf + (size_t)4096 * 2048;       // 4096*2048
  u16* vt  = vbf + (size_t)4096 * 2048;       // 4096*2048
  float* part = (float*)(vt + (size_t)4096 * 2048);  // [32][16][128] f32 col-chunk sums

  k_cast_fused<<<7168, 256, 0, stream>>>(q_in, qbf, W, wtb);
  k_gemm128<<<1024, 512, 0, stream>>>(qbf, wtb, bias, qb, kbf, vbf);
  k_vtrans<<<dim3(16, 32), 256, 0, stream>>>(vbf, vt, part);
  k_attn<<<dim3(32, 32), 256, 0, stream>>>(qb, kbf, vt, part, out);
}